// Round 13
// baseline (268.336 us; speedup 1.0000x reference)
//
#include <hip/hip_runtime.h>
#include <stdint.h>
#include <stddef.h>

typedef __bf16 bf16;
typedef __attribute__((ext_vector_type(8))) __bf16 bf16x8;
typedef __attribute__((ext_vector_type(4))) __bf16 bf16x4;
typedef __attribute__((ext_vector_type(4))) float f32x4;
typedef __attribute__((ext_vector_type(16))) float f32x16;
typedef __attribute__((ext_vector_type(4))) float float4v;
typedef __attribute__((ext_vector_type(4))) uint32_t u32x4;

#define BATCH 4
#define SEQ   2048
#define EMB   1024
#define NH    16
#define HD    64
#define F3    3072   // 3*EMB

#define MFMA16(a, b, c) __builtin_amdgcn_mfma_f32_16x16x32_bf16((a), (b), (c), 0, 0, 0)
#define MFMA32(a, b, c) __builtin_amdgcn_mfma_f32_32x32x16_bf16((a), (b), (c), 0, 0, 0)

// 2^x as a single v_exp_f32, emitted BY THE COMPILER (hazard nops included).
// R10: raw asm hides the TRANS wait-state hazard (wrong results); R9: libm
// exp2f is +30% VALU (OCML range handling). Builtin = correct middle path.
__device__ __forceinline__ float exp2_fast(float x) {
  return __builtin_amdgcn_exp2f(x);
}

// async global->LDS, 16B per lane. lds ptr must be wave-uniform; lane i lands at l + i*16B.
__device__ __forceinline__ void gload_lds16(const bf16* g, bf16* l) {
  __builtin_amdgcn_global_load_lds(
      (const __attribute__((address_space(1))) uint32_t*)g,
      (__attribute__((address_space(3))) uint32_t*)l, 16, 0, 0);
}

// ---------------------------------------------------------------------------
// 32x32 tile transpose+convert helper (shared by prep_kernel and the wo pass).
// ---------------------------------------------------------------------------
__device__ __forceinline__ void transpose_tile32(const float* __restrict__ in,
                                                 bf16* __restrict__ out,
                                                 int R, int C, int bx, int by) {
  __shared__ bf16 tile[32][33];
  const int tx = threadIdx.x & 31;
  const int ty = threadIdx.x >> 5;  // 0..7
  const int c0 = bx * 32, r0 = by * 32;
#pragma unroll
  for (int kk = 0; kk < 4; ++kk) {
    int r = ty + kk * 8;
    tile[r][tx] = (bf16)in[(size_t)(r0 + r) * C + c0 + tx];
  }
  __syncthreads();
#pragma unroll
  for (int kk = 0; kk < 4; ++kk) {
    int r = ty + kk * 8;
    out[(size_t)(c0 + r) * R + r0 + tx] = tile[tx][r];
  }
}

// ---------------------------------------------------------------------------
// Fused prep: region-dispatched by blockIdx.
//   [0, 8192)        : convert x f32 -> bf16 (2M float4 groups, exact fit)
//   [8192, 11264)    : transpose wqkv [1024][3072] f32 -> wqkvT [3072][1024] bf16
//   [11264, 11520)   : RoPE cos/sin table (2048 pos x 32 d1, f32)
// ---------------------------------------------------------------------------
__global__ __launch_bounds__(256) void prep_kernel(const float* __restrict__ x_raw,
                                                   bf16* __restrict__ xb,
                                                   const float* __restrict__ wqkv_raw,
                                                   bf16* __restrict__ wqkvT,
                                                   float* __restrict__ cosT,
                                                   float* __restrict__ sinT) {
  const int blk = blockIdx.x;
  if (blk < 8192) {
    int i = blk * 256 + threadIdx.x;   // 8192*256 == BATCH*SEQ*EMB/4 exactly
    float4v v = ((const float4v*)x_raw)[i];
    bf16x4 o;
#pragma unroll
    for (int k = 0; k < 4; ++k) o[k] = (bf16)v[k];
    ((bf16x4*)xb)[i] = o;
  } else if (blk < 11264) {
    int idx = blk - 8192;              // 3072 tiles: 96 col-tiles x 32 row-tiles
    transpose_tile32(wqkv_raw, wqkvT, EMB, F3, idx % 96, idx / 96);
  } else {
    int idx = (blk - 11264) * 256 + threadIdx.x;   // 65536
    int pos = idx >> 5, d1 = idx & 31;
    float inv = powf(10000.0f, -(float)(2 * d1) / 64.0f);
    float th = (float)pos * inv;
    cosT[idx] = cosf(th);
    sinT[idx] = sinf(th);
  }
}

// ---------------------------------------------------------------------------
// Standalone transpose (wo only; must run after attn frees the woT region).
// ---------------------------------------------------------------------------
__global__ __launch_bounds__(256) void transpose_f32_bf16(const float* __restrict__ in,
                                                          bf16* __restrict__ out,
                                                          int R, int C) {
  transpose_tile32(in, out, R, C, blockIdx.x, blockIdx.y);
}

// ---------------------------------------------------------------------------
// 128x256 / BK=64 2-phase MFMA GEMM core (round-5 verified bytes).
// Triple-buffered 9-slot ring, counted vmcnt(6)/tile, swizzle, setprio.
// ---------------------------------------------------------------------------
__device__ __forceinline__ void gemm128_core(bf16* lds,
                                             const bf16* __restrict__ Abase,
                                             const bf16* __restrict__ Bbase,
                                             f32x4 (&acc)[4][4]) {
  const int tid = threadIdx.x;
  const int w = tid >> 6, lane = tid & 63;
  const int lhi = lane >> 4, llo = lane & 15, l7 = llo & 15 & 7;
  const int wr = w >> 2, wc = w & 3;          // 2M x 4N wave grid
  const int srow = lane >> 3;                 // staging row within 8-row chunk
  const int sk16 = (lane & 7) ^ srow;         // pre-swizzled global 16B granule
  const size_t g_lane = (size_t)(w * 16 + srow) * EMB + sk16 * 8;
  bf16* ldsw = lds + w * 1024;                // wave chunk base within a slot

  const int ka0 = (lhi * 8) ^ (l7 << 3);
  const int ka1 = (32 + lhi * 8) ^ (l7 << 3);
  const int arow = (wr * 64 + llo) * 64;            // A frag row base (elems)
  const int brow = ((wc & 1) * 64 + llo) * 64;      // B frag row base (elems)
  const int bsel = wc >> 1;                         // which B half-slot

#pragma unroll
  for (int i = 0; i < 4; ++i)
#pragma unroll
    for (int j = 0; j < 4; ++j) acc[i][j] = (f32x4){0.f, 0.f, 0.f, 0.f};

#define STAGE(baseptr, slot)                              \
  do {                                                    \
    const bf16* _b = (baseptr);                           \
    bf16* _l = ldsw + (slot) * 8192;                      \
    gload_lds16(_b + g_lane, _l);                         \
    gload_lds16(_b + g_lane + 8 * EMB, _l + 512);         \
  } while (0)

  // prologue: t0 -> slots 0,1,2 ; t1 -> slots 3,4,5
  STAGE(Abase, 0);
  STAGE(Bbase, 1);
  STAGE(Bbase + 128 * EMB, 2);
  STAGE(Abase + 64, 3);
  STAGE(Bbase + 64, 4);
  STAGE(Bbase + 128 * EMB + 64, 5);
  asm volatile("s_waitcnt vmcnt(6)" ::: "memory");  // t0's 6 loads landed
  __builtin_amdgcn_s_barrier();

  int s = 0;  // 3*(t%3)
#pragma unroll 1
  for (int t = 0; t < 16; ++t) {
    const bf16* ldsA = lds + s * 8192 + arow;
    const bf16* ldsB = lds + (s + 1 + bsel) * 8192 + brow;
    const int k2 = (t + 2) * 64;
    int st2 = s + 6;                 // 3*((t+2)%3) = slots of t-1
    if (st2 >= 9) st2 -= 9;
    bf16x8 a[4][2], b0[2][2], b1[2][2];

    // ---- phase 0: n-half0 -> acc[0..3][0..1]
#pragma unroll
    for (int i = 0; i < 4; ++i) {
      a[i][0] = *(const bf16x8*)(ldsA + i * 1024 + ka0);
      a[i][1] = *(const bf16x8*)(ldsA + i * 1024 + ka1);
    }
#pragma unroll
    for (int j = 0; j < 2; ++j) {
      b0[j][0] = *(const bf16x8*)(ldsB + j * 1024 + ka0);
      b0[j][1] = *(const bf16x8*)(ldsB + j * 1024 + ka1);
    }
    if (t < 14) {
      STAGE(Abase + k2, st2);
      STAGE(Bbase + k2, st2 + 1);
    }
    __builtin_amdgcn_s_barrier();
    asm volatile("s_waitcnt lgkmcnt(0)" ::: "memory");
    __builtin_amdgcn_sched_barrier(0);
    __builtin_amdgcn_s_setprio(1);
#pragma unroll
    for (int i = 0; i < 4; ++i)
#pragma unroll
      for (int j = 0; j < 2; ++j) {
        acc[i][j] = MFMA16(a[i][0], b0[j][0], acc[i][j]);
        acc[i][j] = MFMA16(a[i][1], b0[j][1], acc[i][j]);
      }
    __builtin_amdgcn_s_setprio(0);
    __builtin_amdgcn_s_barrier();

    // ---- phase 1: n-half1 -> acc[0..3][2..3]
#pragma unroll
    for (int j = 0; j < 2; ++j) {
      b1[j][0] = *(const bf16x8*)(ldsB + 2048 + j * 1024 + ka0);
      b1[j][1] = *(const bf16x8*)(ldsB + 2048 + j * 1024 + ka1);
    }
    if (t < 14) STAGE(Bbase + 128 * EMB + k2, st2 + 2);
    __builtin_amdgcn_s_barrier();
    asm volatile("s_waitcnt lgkmcnt(0)" ::: "memory");
    __builtin_amdgcn_sched_barrier(0);
    __builtin_amdgcn_s_setprio(1);
#pragma unroll
    for (int i = 0; i < 4; ++i)
#pragma unroll
      for (int j = 0; j < 2; ++j) {
        acc[i][2 + j] = MFMA16(a[i][0], b1[j][0], acc[i][2 + j]);
        acc[i][2 + j] = MFMA16(a[i][1], b1[j][1], acc[i][2 + j]);
      }
    __builtin_amdgcn_s_setprio(0);
    if (t < 14) {
      asm volatile("s_waitcnt vmcnt(6)" ::: "memory");
    } else if (t == 14) {
      asm volatile("s_waitcnt vmcnt(0)" ::: "memory");
    }
    if (t < 15) __builtin_amdgcn_s_barrier();

    s += 3;
    if (s >= 9) s -= 9;
  }
#undef STAGE
}

// ---------------------------------------------------------------------------
// QKV GEMM (128x256 core) + bias + RoPE + scatter epilogue.
// Grid 768 (64 Mtiles x 12 Ntiles) = exactly 3 rounds @ 1 blk/CU; 768%8==0.
// Q is prescaled by 0.125*log2(e) so attn can use v_exp_f32 (2^x) directly.
// ---------------------------------------------------------------------------
__global__ __launch_bounds__(512, 2) void qkv128_kernel(
    const bf16* __restrict__ x, const bf16* __restrict__ wT,
    const float* __restrict__ bias, bf16* __restrict__ qo, bf16* __restrict__ ko,
    bf16* __restrict__ vo, const float* __restrict__ cosT,
    const float* __restrict__ sinT) {
  extern __shared__ __align__(16) bf16 ldsb[];
  const int orig = blockIdx.x;
  const int wg = (orig & 7) * 96 + (orig >> 3);   // 96 contiguous wgs per XCD
  const int bx = wg % 12, by = wg / 12;
  const int row_a0 = by * 128, row_b0 = bx * 256;

  f32x4 acc[4][4];
  gemm128_core(ldsb, x + (size_t)row_a0 * EMB, wT + (size_t)row_b0 * EMB, acc);

  const int tid = threadIdx.x;
  const int w = tid >> 6, lane = tid & 63;
  const int lhi = lane >> 4, llo = lane & 15;
  const int wr = w >> 2, wc = w & 3;

  const int f0 = row_b0 + wc * 64;      // wave col base, 64-aligned
  const int part = f0 >> 10;            // 0=Q 1=K 2=V
  const int hh = (f0 & 1023) >> 6;      // head
  const int m_base = row_a0 + wr * 64;

  float bvals[4];
#pragma unroll
  for (int j = 0; j < 4; ++j) bvals[j] = bias[f0 + j * 16 + llo];

  if (part == 2) {
#pragma unroll
    for (int mi = 0; mi < 4; ++mi) {
      int m0 = m_base + mi * 16 + lhi * 4;
      int bb = m0 >> 11, pos0 = m0 & 2047;
#pragma unroll
      for (int j = 0; j < 4; ++j) {
        int dd = j * 16 + llo;
        bf16x4 pk;
#pragma unroll
        for (int r = 0; r < 4; ++r) pk[r] = (bf16)(acc[mi][j][r] + bvals[j]);
        *(bf16x4*)(vo + ((size_t)(bb * NH + hh) * HD + dd) * SEQ + pos0) = pk;
      }
    }
  } else {
    bf16* dst = (part == 0) ? qo : ko;
    // exp2 fold: Q carries 1/sqrt(64) * log2(e) so attn uses v_exp_f32 (2^x)
    // without the per-score multiply. K unscaled. (Numerics verified R9/R11.)
    const float qs = (part == 0) ? 0.18033688f : 1.0f;
#pragma unroll
    for (int mi = 0; mi < 4; ++mi) {
#pragma unroll
      for (int r = 0; r < 4; ++r) {
        int m = m_base + mi * 16 + lhi * 4 + r;
        int bb = m >> 11, pos = m & 2047;
        size_t base = ((size_t)(bb * NH + hh) * SEQ + pos) * HD;
#pragma unroll
        for (int j = 0; j < 2; ++j) {
          int d1 = j * 16 + llo;
          float x1 = acc[mi][j][r] + bvals[j];
          float x2 = acc[mi][j + 2][r] + bvals[j + 2];
          float cth = cosT[pos * 32 + d1];
          float sth = sinT[pos * 32 + d1];
          dst[base + d1] = (bf16)((x1 * cth - x2 * sth) * qs);
          dst[base + d1 + 32] = (bf16)((x2 * cth + x1 * sth) * qs);
        }
      }
    }
  }
}

// ---------------------------------------------------------------------------
// Output projection on the 128x256 core. Grid 256 (64 x 4) = full GPU.
// ---------------------------------------------------------------------------
__global__ __launch_bounds__(512, 2) void outproj128_kernel(
    const bf16* __restrict__ a_in, const bf16* __restrict__ wT,
    const float* __restrict__ bo, float* __restrict__ out) {
  extern __shared__ __align__(16) bf16 ldsb[];
  const int orig = blockIdx.x;
  const int wg = (orig & 7) * 32 + (orig >> 3);   // 256 % 8 == 0
  const int bx = wg % 4, by = wg / 4;
  const int row_a0 = by * 128, row_b0 = bx * 256;

  f32x4 acc[4][4];
  gemm128_core(ldsb, a_in + (size_t)row_a0 * EMB, wT + (size_t)row_b0 * EMB, acc);

  const int tid = threadIdx.x;
  const int w = tid >> 6, lane = tid & 63;
  const int lhi = lane >> 4, llo = lane & 15;
  const int wr = w >> 2, wc = w & 3;

  const int col0 = row_b0 + wc * 64;
  const int m_base = row_a0 + wr * 64;
  float bvals[4];
#pragma unroll
  for (int j = 0; j < 4; ++j) bvals[j] = bo[col0 + j * 16 + llo];
#pragma unroll
  for (int mi = 0; mi < 4; ++mi) {
#pragma unroll
    for (int r = 0; r < 4; ++r) {
      int m = m_base + mi * 16 + lhi * 4 + r;
#pragma unroll
      for (int j = 0; j < 4; ++j)
        out[(size_t)m * EMB + col0 + j * 16 + llo] = acc[mi][j][r] + bvals[j];
    }
  }
}

// ---------------------------------------------------------------------------
// Flash attention v6: v5g per-wave code (verified R11) with 4-wave blocks,
// QBLK=128, grid 1024 = exactly 4 blocks/CU. Counters (R11: VALU 46%, MFMA
// 37%, ~50% no-issue) say barrier/latency-bound with only 2 independent
// barrier groups per CU; 4 smaller blocks quadruple the independent groups
// at the same wave count. Per-wave work/layout/swizzle byte-identical; only
// the staging wave->chunk map (waves 0-1 K x4 chunks, 2-3 V x4), Q base,
// XCD remap, and epilogue pos change. LDS unchanged 32KB/block.
// (R12 submission of this exact source hit an infra "container failed twice"
// error with no test verdict; resubmitted unchanged — audit found no hang
// vector: bounded loops, uniform barriers, bijective remap, in-bounds addrs.)
// ---------------------------------------------------------------------------
__global__ __launch_bounds__(256, 2) void attn32_kernel(const bf16* __restrict__ q,
                                                        const bf16* __restrict__ k,
                                                        const bf16* __restrict__ vT,
                                                        bf16* __restrict__ o) {
  __shared__ __align__(16) bf16 smem[16384];  // K dbuf 2x4096, V dbuf 2x4096 elems

  const int tid = threadIdx.x, w = tid >> 6, lane = tid & 63;
  const int l31 = lane & 31, hi = lane >> 5;
  const int bidx = blockIdx.x;
  const int vblk = (bidx & 7) * 128 + (bidx >> 3);  // XCD-contiguous remap (1024 blocks)
  const int qt = vblk & 15, bh = vblk >> 4;         // 16 q-tiles of 128, bh in [0,64)
  const bf16* qbase = q + (size_t)bh * SEQ * HD + qt * 128 * HD;
  const bf16* kbase = k + (size_t)bh * SEQ * HD;
  const bf16* vbase = vT + (size_t)bh * HD * SEQ;

  const int rowc = lane >> 3;                     // row within 8-row chunk
  const int sw8 = (lane & 7) ^ rowc;              // staging XOR swizzle (16B granules)

  // Q -> registers: B-frag qf[c] = Q[q=l31][c*16 + hi*8 + j], rows w*32+l31
  bf16x8 qf[4];
  {
    const bf16* qrow = qbase + (size_t)(w * 32 + l31) * HD;
#pragma unroll
    for (int c = 0; c < 4; ++c) qf[c] = *(const bf16x8*)(qrow + c * 16 + hi * 8);
  }

  // stage tile 0: waves 0-1 K (64tok x 64d, 4 chunks each), waves 2-3 V^T
  if (w < 2) {
#pragma unroll
    for (int c = 0; c < 4; ++c) {
      int ch = w * 4 + c, row = ch * 8 + rowc;
      gload_lds16(kbase + (size_t)row * HD + sw8 * 8, &smem[ch * 512]);
    }
  } else {
#pragma unroll
    for (int c = 0; c < 4; ++c) {
      int ch = (w - 2) * 4 + c, row = ch * 8 + rowc;
      gload_lds16(vbase + (size_t)row * SEQ + sw8 * 8, &smem[8192 + ch * 512]);
    }
  }
  __syncthreads();

  float rsum = 0.f;
  f32x16 oacc[2];
#pragma unroll
  for (int r = 0; r < 16; ++r) { oacc[0][r] = 0.f; oacc[1][r] = 0.f; }

  const int swz = (l31 & 7);  // row&7 for frag reads (rows = tile_base + l31)

  for (int kb = 0; kb < 32; ++kb) {
    bf16* Kc = smem + (kb & 1) * 4096;
    bf16* Vc = smem + 8192 + (kb & 1) * 4096;
    // prefetch next tile into alt buffers
    if (kb < 31) {
      int kpos = (kb + 1) * 64;
      if (w < 2) {
        bf16* Kn = smem + ((kb + 1) & 1) * 4096;
#pragma unroll
        for (int c = 0; c < 4; ++c) {
          int ch = w * 4 + c, row = ch * 8 + rowc;
          gload_lds16(kbase + (size_t)(kpos + row) * HD + sw8 * 8, &Kn[ch * 512]);
        }
      } else {
        bf16* Vn = smem + 8192 + ((kb + 1) & 1) * 4096;
#pragma unroll
        for (int c = 0; c < 4; ++c) {
          int ch = (w - 2) * 4 + c, row = ch * 8 + rowc;
          gload_lds16(vbase + (size_t)row * SEQ + kpos + sw8 * 8, &Vn[ch * 512]);
        }
      }
    }

    // ---- QK^T: S^T[tok][q], token tiles tt=0,1; k-chunks c of 16 dims
    f32x16 st0, st1;
#pragma unroll
    for (int r = 0; r < 16; ++r) { st0[r] = 0.f; st1[r] = 0.f; }
    __builtin_amdgcn_s_setprio(1);
#pragma unroll
    for (int c = 0; c < 4; ++c) {
      bf16x8 kf0 = *(const bf16x8*)&Kc[l31 * 64 + (((c * 2 + hi) ^ swz) * 8)];
      bf16x8 kf1 = *(const bf16x8*)&Kc[(32 + l31) * 64 + (((c * 2 + hi) ^ swz) * 8)];
      st0 = MFMA32(kf0, qf[c], st0);
      st1 = MFMA32(kf1, qf[c], st1);
    }
    __builtin_amdgcn_s_setprio(0);

    // ---- softmax: p = 2^s via builtin exp2 (Q prescaled by log2e/8)
#pragma unroll
    for (int r = 0; r < 16; ++r) {
      st0[r] = exp2_fast(st0[r]);
      st1[r] = exp2_fast(st1[r]);
    }
    {
      float a0 = 0.f, a1 = 0.f, a2 = 0.f, a3 = 0.f;
#pragma unroll
      for (int r = 0; r < 16; r += 4) {
        a0 += st0[r];     a1 += st0[r + 1];
        a2 += st0[r + 2]; a3 += st0[r + 3];
      }
#pragma unroll
      for (int r = 0; r < 16; r += 4) {
        a0 += st1[r];     a1 += st1[r + 1];
        a2 += st1[r + 2]; a3 += st1[r + 3];
      }
      rsum += (a0 + a1) + (a2 + a3);
    }

    // ---- P -> PV A-frags (T12): per (tt,c1): 4 cvt_pk + 2 permlane32_swap.
    bf16x8 pa[4];
#pragma unroll
    for (int tt = 0; tt < 2; ++tt) {
#pragma unroll
      for (int c1 = 0; c1 < 2; ++c1) {
        float s0 = tt ? st1[c1 * 8 + 0] : st0[c1 * 8 + 0];
        float s1 = tt ? st1[c1 * 8 + 1] : st0[c1 * 8 + 1];
        float s2 = tt ? st1[c1 * 8 + 2] : st0[c1 * 8 + 2];
        float s3 = tt ? st1[c1 * 8 + 3] : st0[c1 * 8 + 3];
        float s4 = tt ? st1[c1 * 8 + 4] : st0[c1 * 8 + 4];
        float s5 = tt ? st1[c1 * 8 + 5] : st0[c1 * 8 + 5];
        float s6 = tt ? st1[c1 * 8 + 6] : st0[c1 * 8 + 6];
        float s7 = tt ? st1[c1 * 8 + 7] : st0[c1 * 8 + 7];
        uint32_t a0, a1, b0, b1;
        asm("v_cvt_pk_bf16_f32 %0, %1, %2" : "=v"(a0) : "v"(s0), "v"(s1));
        asm("v_cvt_pk_bf16_f32 %0, %1, %2" : "=v"(a1) : "v"(s2), "v"(s3));
        asm("v_cvt_pk_bf16_f32 %0, %1, %2" : "=v"(b0) : "v"(s4), "v"(s5));
        asm("v_cvt_pk_bf16_f32 %0, %1, %2" : "=v"(b1) : "v"(s6), "v"(s7));
        asm("v_permlane32_swap_b32 %0, %1" : "+v"(a0), "+v"(b0));
        asm("v_permlane32_swap_b32 %0, %1" : "+v"(a1), "+v"(b1));
        u32x4 uv = {a0, a1, b0, b1};
        pa[tt * 2 + c1] = __builtin_bit_cast(bf16x8, uv);
      }
    }

    // ---- O += P V : A=pa[c] (tokens c*16..+15), B=V^T rows d=jt*32+l31
    __builtin_amdgcn_s_setprio(1);
#pragma unroll
    for (int c = 0; c < 4; ++c) {
      bf16x8 v0 = *(const bf16x8*)&Vc[l31 * 64 + (((c * 2 + hi) ^ swz) * 8)];
      bf16x8 v1 = *(const bf16x8*)&Vc[(32 + l31) * 64 + (((c * 2 + hi) ^ swz) * 8)];
      oacc[0] = MFMA32(pa[c], v0, oacc[0]);
      oacc[1] = MFMA32(pa[c], v1, oacc[1]);
    }
    __builtin_amdgcn_s_setprio(0);

    __syncthreads();  // prefetch landed + guards buffer reuse
  }

  // epilogue: rsum(q=l31) split across lane halves -> combine; redistribute
  // to C-layout row owners via shfl; normalize and write.
  rsum += __shfl_xor(rsum, 32);
  const int bb = bh >> 4, hh = bh & 15;
#pragma unroll
  for (int r = 0; r < 16; ++r) {
    int qrow = (r & 3) + 8 * (r >> 2) + 4 * hi;
    float inv = 1.0f / __shfl(rsum, qrow);
    int pos = qt * 128 + w * 32 + qrow;
    size_t base = ((size_t)bb * SEQ + pos) * EMB + hh * HD;
    o[base + l31] = (bf16)(oacc[0][r] * inv);
    o[base + 32 + l31] = (bf16)(oacc[1][r] * inv);
  }
}

// ---------------------------------------------------------------------------
// Workspace layout (<= 64 MiB used):
//   [0, 16M)   qw [b,h,s,d] bf16   (later woT @0..2M after attn)
//   [16M,32M)  kw;  [32M,48M) vw [b,h,d,s]
//   [48M,64M)  phase1-2: wqkvT (6M) + cosT/sinT; phase3-4: ow bf16 (16M)
// d_out (33.5 MB f32) doubles as xb scratch (16.8 MB bf16) in phases 1-2.
// ---------------------------------------------------------------------------
extern "C" void kernel_launch(void* const* d_in, const int* in_sizes, int n_in,
                              void* d_out, int out_size, void* d_ws, size_t ws_size,
                              hipStream_t stream) {
  const float* x_raw = (const float*)d_in[0];
  const float* wqkv_raw = (const float*)d_in[1];
  const float* bqkv = (const float*)d_in[2];
  const float* wo_raw = (const float*)d_in[3];
  const float* bo = (const float*)d_in[4];
  float* out = (float*)d_out;

  char* ws = (char*)d_ws;
  bf16* qw = (bf16*)(ws);                       // 16 MiB
  bf16* kw = (bf16*)(ws + 16777216);            // 16 MiB
  bf16* vw = (bf16*)(ws + 33554432);            // 16 MiB
  bf16* wqkvT = (bf16*)(ws + 50331648);         // 6 MiB (phase 1-2)
  float* cosT = (float*)(ws + 56623104);        // 256 KiB (phase 1-2)
  float* sinT = (float*)(ws + 56885248);        // 256 KiB (phase 1-2)
  bf16* ow = (bf16*)(ws + 50331648);            // 16 MiB (phase 3-4, overlays above)
  bf16* woT = (bf16*)(ws);                      // 2 MiB (phase 3.5-4, overlays qw)
  bf16* xb = (bf16*)d_out;                      // 16.8 MiB scratch in d_out (phase 1-2)

  static bool attr_set = false;
  if (!attr_set) {
    (void)hipFuncSetAttribute((const void*)qkv128_kernel,
                              hipFuncAttributeMaxDynamicSharedMemorySize, 163840);
    (void)hipFuncSetAttribute((const void*)outproj128_kernel,
                              hipFuncAttributeMaxDynamicSharedMemorySize, 163840);
    attr_set = true;
  }

  prep_kernel<<<11520, 256, 0, stream>>>(x_raw, xb, wqkv_raw, wqkvT, cosT, sinT);

  qkv128_kernel<<<dim3((BATCH * SEQ / 128) * (F3 / 256)), 512, 147456, stream>>>(
      xb, wqkvT, bqkv, qw, kw, vw, cosT, sinT);
  attn32_kernel<<<dim3(BATCH * NH * (SEQ / 128)), 256, 0, stream>>>(qw, kw, vw, ow);

  transpose_f32_bf16<<<dim3(EMB / 32, EMB / 32), 256, 0, stream>>>(wo_raw, woT, EMB, EMB);
  outproj128_kernel<<<dim3((BATCH * SEQ / 128) * (EMB / 256)), 512, 147456, stream>>>(
      ow, woT, bo, out);
}

// Round 14
// 254.098 us; speedup vs baseline: 1.0560x; 1.0560x over previous
//
#include <hip/hip_runtime.h>
#include <stdint.h>
#include <stddef.h>

typedef __bf16 bf16;
typedef __attribute__((ext_vector_type(8))) __bf16 bf16x8;
typedef __attribute__((ext_vector_type(4))) __bf16 bf16x4;
typedef __attribute__((ext_vector_type(4))) float f32x4;
typedef __attribute__((ext_vector_type(16))) float f32x16;
typedef __attribute__((ext_vector_type(4))) float float4v;
typedef __attribute__((ext_vector_type(4))) uint32_t u32x4;

#define BATCH 4
#define SEQ   2048
#define EMB   1024
#define NH    16
#define HD    64
#define F3    3072   // 3*EMB

#define MFMA16(a, b, c) __builtin_amdgcn_mfma_f32_16x16x32_bf16((a), (b), (c), 0, 0, 0)
#define MFMA32(a, b, c) __builtin_amdgcn_mfma_f32_32x32x16_bf16((a), (b), (c), 0, 0, 0)

// 2^x as a single v_exp_f32, emitted BY THE COMPILER (hazard nops included).
// R10: raw asm hides the TRANS wait-state hazard (wrong results); R9: libm
// exp2f is +30% VALU (OCML range handling). Builtin = correct middle path.
__device__ __forceinline__ float exp2_fast(float x) {
  return __builtin_amdgcn_exp2f(x);
}

// async global->LDS, 16B per lane. lds ptr must be wave-uniform; lane i lands at l + i*16B.
__device__ __forceinline__ void gload_lds16(const bf16* g, bf16* l) {
  __builtin_amdgcn_global_load_lds(
      (const __attribute__((address_space(1))) uint32_t*)g,
      (__attribute__((address_space(3))) uint32_t*)l, 16, 0, 0);
}

// ---------------------------------------------------------------------------
// 32x32 tile transpose+convert helper (shared by prep_kernel and the wo pass).
// ---------------------------------------------------------------------------
__device__ __forceinline__ void transpose_tile32(const float* __restrict__ in,
                                                 bf16* __restrict__ out,
                                                 int R, int C, int bx, int by) {
  __shared__ bf16 tile[32][33];
  const int tx = threadIdx.x & 31;
  const int ty = threadIdx.x >> 5;  // 0..7
  const int c0 = bx * 32, r0 = by * 32;
#pragma unroll
  for (int kk = 0; kk < 4; ++kk) {
    int r = ty + kk * 8;
    tile[r][tx] = (bf16)in[(size_t)(r0 + r) * C + c0 + tx];
  }
  __syncthreads();
#pragma unroll
  for (int kk = 0; kk < 4; ++kk) {
    int r = ty + kk * 8;
    out[(size_t)(c0 + r) * R + r0 + tx] = tile[tx][r];
  }
}

// ---------------------------------------------------------------------------
// Fused prep: region-dispatched by blockIdx.
//   [0, 8192)        : convert x f32 -> bf16 (2M float4 groups, exact fit)
//   [8192, 11264)    : transpose wqkv [1024][3072] f32 -> wqkvT [3072][1024] bf16
//   [11264, 11520)   : RoPE cos/sin table (2048 pos x 32 d1, f32)
// ---------------------------------------------------------------------------
__global__ __launch_bounds__(256) void prep_kernel(const float* __restrict__ x_raw,
                                                   bf16* __restrict__ xb,
                                                   const float* __restrict__ wqkv_raw,
                                                   bf16* __restrict__ wqkvT,
                                                   float* __restrict__ cosT,
                                                   float* __restrict__ sinT) {
  const int blk = blockIdx.x;
  if (blk < 8192) {
    int i = blk * 256 + threadIdx.x;   // 8192*256 == BATCH*SEQ*EMB/4 exactly
    float4v v = ((const float4v*)x_raw)[i];
    bf16x4 o;
#pragma unroll
    for (int k = 0; k < 4; ++k) o[k] = (bf16)v[k];
    ((bf16x4*)xb)[i] = o;
  } else if (blk < 11264) {
    int idx = blk - 8192;              // 3072 tiles: 96 col-tiles x 32 row-tiles
    transpose_tile32(wqkv_raw, wqkvT, EMB, F3, idx % 96, idx / 96);
  } else {
    int idx = (blk - 11264) * 256 + threadIdx.x;   // 65536
    int pos = idx >> 5, d1 = idx & 31;
    float inv = powf(10000.0f, -(float)(2 * d1) / 64.0f);
    float th = (float)pos * inv;
    cosT[idx] = cosf(th);
    sinT[idx] = sinf(th);
  }
}

// ---------------------------------------------------------------------------
// Standalone transpose (wo only; must run after attn frees the woT region).
// ---------------------------------------------------------------------------
__global__ __launch_bounds__(256) void transpose_f32_bf16(const float* __restrict__ in,
                                                          bf16* __restrict__ out,
                                                          int R, int C) {
  transpose_tile32(in, out, R, C, blockIdx.x, blockIdx.y);
}

// ---------------------------------------------------------------------------
// 128x256 / BK=64 2-phase MFMA GEMM core (round-5 verified bytes).
// Triple-buffered 9-slot ring, counted vmcnt(6)/tile, swizzle, setprio.
// ---------------------------------------------------------------------------
__device__ __forceinline__ void gemm128_core(bf16* lds,
                                             const bf16* __restrict__ Abase,
                                             const bf16* __restrict__ Bbase,
                                             f32x4 (&acc)[4][4]) {
  const int tid = threadIdx.x;
  const int w = tid >> 6, lane = tid & 63;
  const int lhi = lane >> 4, llo = lane & 15, l7 = llo & 15 & 7;
  const int wr = w >> 2, wc = w & 3;          // 2M x 4N wave grid
  const int srow = lane >> 3;                 // staging row within 8-row chunk
  const int sk16 = (lane & 7) ^ srow;         // pre-swizzled global 16B granule
  const size_t g_lane = (size_t)(w * 16 + srow) * EMB + sk16 * 8;
  bf16* ldsw = lds + w * 1024;                // wave chunk base within a slot

  const int ka0 = (lhi * 8) ^ (l7 << 3);
  const int ka1 = (32 + lhi * 8) ^ (l7 << 3);
  const int arow = (wr * 64 + llo) * 64;            // A frag row base (elems)
  const int brow = ((wc & 1) * 64 + llo) * 64;      // B frag row base (elems)
  const int bsel = wc >> 1;                         // which B half-slot

#pragma unroll
  for (int i = 0; i < 4; ++i)
#pragma unroll
    for (int j = 0; j < 4; ++j) acc[i][j] = (f32x4){0.f, 0.f, 0.f, 0.f};

#define STAGE(baseptr, slot)                              \
  do {                                                    \
    const bf16* _b = (baseptr);                           \
    bf16* _l = ldsw + (slot) * 8192;                      \
    gload_lds16(_b + g_lane, _l);                         \
    gload_lds16(_b + g_lane + 8 * EMB, _l + 512);         \
  } while (0)

  // prologue: t0 -> slots 0,1,2 ; t1 -> slots 3,4,5
  STAGE(Abase, 0);
  STAGE(Bbase, 1);
  STAGE(Bbase + 128 * EMB, 2);
  STAGE(Abase + 64, 3);
  STAGE(Bbase + 64, 4);
  STAGE(Bbase + 128 * EMB + 64, 5);
  asm volatile("s_waitcnt vmcnt(6)" ::: "memory");  // t0's 6 loads landed
  __builtin_amdgcn_s_barrier();

  int s = 0;  // 3*(t%3)
#pragma unroll 1
  for (int t = 0; t < 16; ++t) {
    const bf16* ldsA = lds + s * 8192 + arow;
    const bf16* ldsB = lds + (s + 1 + bsel) * 8192 + brow;
    const int k2 = (t + 2) * 64;
    int st2 = s + 6;                 // 3*((t+2)%3) = slots of t-1
    if (st2 >= 9) st2 -= 9;
    bf16x8 a[4][2], b0[2][2], b1[2][2];

    // ---- phase 0: n-half0 -> acc[0..3][0..1]
#pragma unroll
    for (int i = 0; i < 4; ++i) {
      a[i][0] = *(const bf16x8*)(ldsA + i * 1024 + ka0);
      a[i][1] = *(const bf16x8*)(ldsA + i * 1024 + ka1);
    }
#pragma unroll
    for (int j = 0; j < 2; ++j) {
      b0[j][0] = *(const bf16x8*)(ldsB + j * 1024 + ka0);
      b0[j][1] = *(const bf16x8*)(ldsB + j * 1024 + ka1);
    }
    if (t < 14) {
      STAGE(Abase + k2, st2);
      STAGE(Bbase + k2, st2 + 1);
    }
    __builtin_amdgcn_s_barrier();
    asm volatile("s_waitcnt lgkmcnt(0)" ::: "memory");
    __builtin_amdgcn_sched_barrier(0);
    __builtin_amdgcn_s_setprio(1);
#pragma unroll
    for (int i = 0; i < 4; ++i)
#pragma unroll
      for (int j = 0; j < 2; ++j) {
        acc[i][j] = MFMA16(a[i][0], b0[j][0], acc[i][j]);
        acc[i][j] = MFMA16(a[i][1], b0[j][1], acc[i][j]);
      }
    __builtin_amdgcn_s_setprio(0);
    __builtin_amdgcn_s_barrier();

    // ---- phase 1: n-half1 -> acc[0..3][2..3]
#pragma unroll
    for (int j = 0; j < 2; ++j) {
      b1[j][0] = *(const bf16x8*)(ldsB + 2048 + j * 1024 + ka0);
      b1[j][1] = *(const bf16x8*)(ldsB + 2048 + j * 1024 + ka1);
    }
    if (t < 14) STAGE(Bbase + 128 * EMB + k2, st2 + 2);
    __builtin_amdgcn_s_barrier();
    asm volatile("s_waitcnt lgkmcnt(0)" ::: "memory");
    __builtin_amdgcn_sched_barrier(0);
    __builtin_amdgcn_s_setprio(1);
#pragma unroll
    for (int i = 0; i < 4; ++i)
#pragma unroll
      for (int j = 0; j < 2; ++j) {
        acc[i][2 + j] = MFMA16(a[i][0], b1[j][0], acc[i][2 + j]);
        acc[i][2 + j] = MFMA16(a[i][1], b1[j][1], acc[i][2 + j]);
      }
    __builtin_amdgcn_s_setprio(0);
    if (t < 14) {
      asm volatile("s_waitcnt vmcnt(6)" ::: "memory");
    } else if (t == 14) {
      asm volatile("s_waitcnt vmcnt(0)" ::: "memory");
    }
    if (t < 15) __builtin_amdgcn_s_barrier();

    s += 3;
    if (s >= 9) s -= 9;
  }
#undef STAGE
}

// ---------------------------------------------------------------------------
// QKV GEMM (128x256 core) + bias + RoPE + scatter epilogue.
// Grid 768 (64 Mtiles x 12 Ntiles) = exactly 3 rounds @ 1 blk/CU; 768%8==0.
// Q is prescaled by 0.125*log2(e) so attn can use v_exp_f32 (2^x) directly.
// ---------------------------------------------------------------------------
__global__ __launch_bounds__(512, 2) void qkv128_kernel(
    const bf16* __restrict__ x, const bf16* __restrict__ wT,
    const float* __restrict__ bias, bf16* __restrict__ qo, bf16* __restrict__ ko,
    bf16* __restrict__ vo, const float* __restrict__ cosT,
    const float* __restrict__ sinT) {
  extern __shared__ __align__(16) bf16 ldsb[];
  const int orig = blockIdx.x;
  const int wg = (orig & 7) * 96 + (orig >> 3);   // 96 contiguous wgs per XCD
  const int bx = wg % 12, by = wg / 12;
  const int row_a0 = by * 128, row_b0 = bx * 256;

  f32x4 acc[4][4];
  gemm128_core(ldsb, x + (size_t)row_a0 * EMB, wT + (size_t)row_b0 * EMB, acc);

  const int tid = threadIdx.x;
  const int w = tid >> 6, lane = tid & 63;
  const int lhi = lane >> 4, llo = lane & 15;
  const int wr = w >> 2, wc = w & 3;

  const int f0 = row_b0 + wc * 64;      // wave col base, 64-aligned
  const int part = f0 >> 10;            // 0=Q 1=K 2=V
  const int hh = (f0 & 1023) >> 6;      // head
  const int m_base = row_a0 + wr * 64;

  float bvals[4];
#pragma unroll
  for (int j = 0; j < 4; ++j) bvals[j] = bias[f0 + j * 16 + llo];

  if (part == 2) {
#pragma unroll
    for (int mi = 0; mi < 4; ++mi) {
      int m0 = m_base + mi * 16 + lhi * 4;
      int bb = m0 >> 11, pos0 = m0 & 2047;
#pragma unroll
      for (int j = 0; j < 4; ++j) {
        int dd = j * 16 + llo;
        bf16x4 pk;
#pragma unroll
        for (int r = 0; r < 4; ++r) pk[r] = (bf16)(acc[mi][j][r] + bvals[j]);
        *(bf16x4*)(vo + ((size_t)(bb * NH + hh) * HD + dd) * SEQ + pos0) = pk;
      }
    }
  } else {
    bf16* dst = (part == 0) ? qo : ko;
    // exp2 fold: Q carries 1/sqrt(64) * log2(e) so attn uses v_exp_f32 (2^x)
    // without the per-score multiply. K unscaled. (Numerics verified R9/R11.)
    const float qs = (part == 0) ? 0.18033688f : 1.0f;
#pragma unroll
    for (int mi = 0; mi < 4; ++mi) {
#pragma unroll
      for (int r = 0; r < 4; ++r) {
        int m = m_base + mi * 16 + lhi * 4 + r;
        int bb = m >> 11, pos = m & 2047;
        size_t base = ((size_t)(bb * NH + hh) * SEQ + pos) * HD;
#pragma unroll
        for (int j = 0; j < 2; ++j) {
          int d1 = j * 16 + llo;
          float x1 = acc[mi][j][r] + bvals[j];
          float x2 = acc[mi][j + 2][r] + bvals[j + 2];
          float cth = cosT[pos * 32 + d1];
          float sth = sinT[pos * 32 + d1];
          dst[base + d1] = (bf16)((x1 * cth - x2 * sth) * qs);
          dst[base + d1 + 32] = (bf16)((x2 * cth + x1 * sth) * qs);
        }
      }
    }
  }
}

// ---------------------------------------------------------------------------
// Output projection on the 128x256 core. Grid 256 (64 x 4) = full GPU.
// ---------------------------------------------------------------------------
__global__ __launch_bounds__(512, 2) void outproj128_kernel(
    const bf16* __restrict__ a_in, const bf16* __restrict__ wT,
    const float* __restrict__ bo, float* __restrict__ out) {
  extern __shared__ __align__(16) bf16 ldsb[];
  const int orig = blockIdx.x;
  const int wg = (orig & 7) * 32 + (orig >> 3);   // 256 % 8 == 0
  const int bx = wg % 4, by = wg / 4;
  const int row_a0 = by * 128, row_b0 = bx * 256;

  f32x4 acc[4][4];
  gemm128_core(ldsb, a_in + (size_t)row_a0 * EMB, wT + (size_t)row_b0 * EMB, acc);

  const int tid = threadIdx.x;
  const int w = tid >> 6, lane = tid & 63;
  const int lhi = lane >> 4, llo = lane & 15;
  const int wr = w >> 2, wc = w & 3;

  const int col0 = row_b0 + wc * 64;
  const int m_base = row_a0 + wr * 64;
  float bvals[4];
#pragma unroll
  for (int j = 0; j < 4; ++j) bvals[j] = bo[col0 + j * 16 + llo];
#pragma unroll
  for (int mi = 0; mi < 4; ++mi) {
#pragma unroll
    for (int r = 0; r < 4; ++r) {
      int m = m_base + mi * 16 + lhi * 4 + r;
#pragma unroll
      for (int j = 0; j < 4; ++j)
        out[(size_t)m * EMB + col0 + j * 16 + llo] = acc[mi][j][r] + bvals[j];
    }
  }
}

// ---------------------------------------------------------------------------
// Flash attention v5g (R11-verified best: 80.6 us, 853 TF): 8 waves x 32
// q-rows, QBLK=256, 32x32x16 MFMA, swapped QK^T, in-register softmax (T12
// cvt_pk+permlane), exp2 fold via compiler builtin. VGPR 60 / occ ~34.5%.
// Attention is CLOSED here: MFMA-ones rsum rejected (R6 occupancy cliff /
// R7 spills), libm+raw-asm exp2 rejected (R9/R10), 4-wave split rejected
// (R13: +5us — smaller barrier groups cost more than they gain).
// ---------------------------------------------------------------------------
__global__ __launch_bounds__(512, 2) void attn32_kernel(const bf16* __restrict__ q,
                                                        const bf16* __restrict__ k,
                                                        const bf16* __restrict__ vT,
                                                        bf16* __restrict__ o) {
  __shared__ __align__(16) bf16 smem[16384];  // K dbuf 2x4096, V dbuf 2x4096 elems

  const int tid = threadIdx.x, w = tid >> 6, lane = tid & 63;
  const int l31 = lane & 31, hi = lane >> 5;
  const int bidx = blockIdx.x;
  const int vblk = (bidx & 7) * 64 + (bidx >> 3);  // XCD-contiguous remap (512 blocks)
  const int qt = vblk & 7, bh = vblk >> 3;         // 8 q-tiles of 256, bh in [0,64)
  const bf16* qbase = q + (size_t)bh * SEQ * HD + qt * 256 * HD;
  const bf16* kbase = k + (size_t)bh * SEQ * HD;
  const bf16* vbase = vT + (size_t)bh * HD * SEQ;

  const int rowc = lane >> 3;                     // row within 8-row chunk
  const int sw8 = (lane & 7) ^ rowc;              // staging XOR swizzle (16B granules)

  // Q -> registers: B-frag qf[c] = Q[q=l31][c*16 + hi*8 + j], rows w*32+l31
  bf16x8 qf[4];
  {
    const bf16* qrow = qbase + (size_t)(w * 32 + l31) * HD;
#pragma unroll
    for (int c = 0; c < 4; ++c) qf[c] = *(const bf16x8*)(qrow + c * 16 + hi * 8);
  }

  // stage tile 0: waves 0-3 K (64tok x 64d), waves 4-7 V^T (64d x 64tok)
  if (w < 4) {
#pragma unroll
    for (int c = 0; c < 2; ++c) {
      int ch = w * 2 + c, row = ch * 8 + rowc;
      gload_lds16(kbase + (size_t)row * HD + sw8 * 8, &smem[ch * 512]);
    }
  } else {
#pragma unroll
    for (int c = 0; c < 2; ++c) {
      int ch = (w - 4) * 2 + c, row = ch * 8 + rowc;
      gload_lds16(vbase + (size_t)row * SEQ + sw8 * 8, &smem[8192 + ch * 512]);
    }
  }
  __syncthreads();

  float rsum = 0.f;
  f32x16 oacc[2];
#pragma unroll
  for (int r = 0; r < 16; ++r) { oacc[0][r] = 0.f; oacc[1][r] = 0.f; }

  const int swz = (l31 & 7);  // row&7 for frag reads (rows = tile_base + l31)

  for (int kb = 0; kb < 32; ++kb) {
    bf16* Kc = smem + (kb & 1) * 4096;
    bf16* Vc = smem + 8192 + (kb & 1) * 4096;
    // prefetch next tile into alt buffers
    if (kb < 31) {
      int kpos = (kb + 1) * 64;
      if (w < 4) {
        bf16* Kn = smem + ((kb + 1) & 1) * 4096;
#pragma unroll
        for (int c = 0; c < 2; ++c) {
          int ch = w * 2 + c, row = ch * 8 + rowc;
          gload_lds16(kbase + (size_t)(kpos + row) * HD + sw8 * 8, &Kn[ch * 512]);
        }
      } else {
        bf16* Vn = smem + 8192 + ((kb + 1) & 1) * 4096;
#pragma unroll
        for (int c = 0; c < 2; ++c) {
          int ch = (w - 4) * 2 + c, row = ch * 8 + rowc;
          gload_lds16(vbase + (size_t)row * SEQ + kpos + sw8 * 8, &Vn[ch * 512]);
        }
      }
    }

    // ---- QK^T: S^T[tok][q], token tiles tt=0,1; k-chunks c of 16 dims
    f32x16 st0, st1;
#pragma unroll
    for (int r = 0; r < 16; ++r) { st0[r] = 0.f; st1[r] = 0.f; }
    __builtin_amdgcn_s_setprio(1);
#pragma unroll
    for (int c = 0; c < 4; ++c) {
      bf16x8 kf0 = *(const bf16x8*)&Kc[l31 * 64 + (((c * 2 + hi) ^ swz) * 8)];
      bf16x8 kf1 = *(const bf16x8*)&Kc[(32 + l31) * 64 + (((c * 2 + hi) ^ swz) * 8)];
      st0 = MFMA32(kf0, qf[c], st0);
      st1 = MFMA32(kf1, qf[c], st1);
    }
    __builtin_amdgcn_s_setprio(0);

    // ---- softmax: p = 2^s via builtin exp2 (Q prescaled by log2e/8)
#pragma unroll
    for (int r = 0; r < 16; ++r) {
      st0[r] = exp2_fast(st0[r]);
      st1[r] = exp2_fast(st1[r]);
    }
    {
      float a0 = 0.f, a1 = 0.f, a2 = 0.f, a3 = 0.f;
#pragma unroll
      for (int r = 0; r < 16; r += 4) {
        a0 += st0[r];     a1 += st0[r + 1];
        a2 += st0[r + 2]; a3 += st0[r + 3];
      }
#pragma unroll
      for (int r = 0; r < 16; r += 4) {
        a0 += st1[r];     a1 += st1[r + 1];
        a2 += st1[r + 2]; a3 += st1[r + 3];
      }
      rsum += (a0 + a1) + (a2 + a3);
    }

    // ---- P -> PV A-frags (T12): per (tt,c1): 4 cvt_pk + 2 permlane32_swap.
    bf16x8 pa[4];
#pragma unroll
    for (int tt = 0; tt < 2; ++tt) {
#pragma unroll
      for (int c1 = 0; c1 < 2; ++c1) {
        float s0 = tt ? st1[c1 * 8 + 0] : st0[c1 * 8 + 0];
        float s1 = tt ? st1[c1 * 8 + 1] : st0[c1 * 8 + 1];
        float s2 = tt ? st1[c1 * 8 + 2] : st0[c1 * 8 + 2];
        float s3 = tt ? st1[c1 * 8 + 3] : st0[c1 * 8 + 3];
        float s4 = tt ? st1[c1 * 8 + 4] : st0[c1 * 8 + 4];
        float s5 = tt ? st1[c1 * 8 + 5] : st0[c1 * 8 + 5];
        float s6 = tt ? st1[c1 * 8 + 6] : st0[c1 * 8 + 6];
        float s7 = tt ? st1[c1 * 8 + 7] : st0[c1 * 8 + 7];
        uint32_t a0, a1, b0, b1;
        asm("v_cvt_pk_bf16_f32 %0, %1, %2" : "=v"(a0) : "v"(s0), "v"(s1));
        asm("v_cvt_pk_bf16_f32 %0, %1, %2" : "=v"(a1) : "v"(s2), "v"(s3));
        asm("v_cvt_pk_bf16_f32 %0, %1, %2" : "=v"(b0) : "v"(s4), "v"(s5));
        asm("v_cvt_pk_bf16_f32 %0, %1, %2" : "=v"(b1) : "v"(s6), "v"(s7));
        asm("v_permlane32_swap_b32 %0, %1" : "+v"(a0), "+v"(b0));
        asm("v_permlane32_swap_b32 %0, %1" : "+v"(a1), "+v"(b1));
        u32x4 uv = {a0, a1, b0, b1};
        pa[tt * 2 + c1] = __builtin_bit_cast(bf16x8, uv);
      }
    }

    // ---- O += P V : A=pa[c] (tokens c*16..+15), B=V^T rows d=jt*32+l31
    __builtin_amdgcn_s_setprio(1);
#pragma unroll
    for (int c = 0; c < 4; ++c) {
      bf16x8 v0 = *(const bf16x8*)&Vc[l31 * 64 + (((c * 2 + hi) ^ swz) * 8)];
      bf16x8 v1 = *(const bf16x8*)&Vc[(32 + l31) * 64 + (((c * 2 + hi) ^ swz) * 8)];
      oacc[0] = MFMA32(pa[c], v0, oacc[0]);
      oacc[1] = MFMA32(pa[c], v1, oacc[1]);
    }
    __builtin_amdgcn_s_setprio(0);

    __syncthreads();  // prefetch landed + guards buffer reuse
  }

  // epilogue: rsum(q=l31) split across lane halves -> combine; redistribute
  // to C-layout row owners via shfl; normalize and write.
  rsum += __shfl_xor(rsum, 32);
  const int bb = bh >> 4, hh = bh & 15;
#pragma unroll
  for (int r = 0; r < 16; ++r) {
    int qrow = (r & 3) + 8 * (r >> 2) + 4 * hi;
    float inv = 1.0f / __shfl(rsum, qrow);
    int pos = qt * 256 + w * 32 + qrow;
    size_t base = ((size_t)bb * SEQ + pos) * EMB + hh * HD;
    o[base + l31] = (bf16)(oacc[0][r] * inv);
    o[base + 32 + l31] = (bf16)(oacc[1][r] * inv);
  }
}

// ---------------------------------------------------------------------------
// Workspace layout (<= 64 MiB used):
//   [0, 16M)   qw [b,h,s,d] bf16   (later woT @0..2M after attn)
//   [16M,32M)  kw;  [32M,48M) vw [b,h,d,s]
//   [48M,64M)  phase1-2: wqkvT (6M) + cosT/sinT; phase3-4: ow bf16 (16M)
// d_out (33.5 MB f32) doubles as xb scratch (16.8 MB bf16) in phases 1-2.
// ---------------------------------------------------------------------------
extern "C" void kernel_launch(void* const* d_in, const int* in_sizes, int n_in,
                              void* d_out, int out_size, void* d_ws, size_t ws_size,
                              hipStream_t stream) {
  const float* x_raw = (const float*)d_in[0];
  const float* wqkv_raw = (const float*)d_in[1];
  const float* bqkv = (const float*)d_in[2];
  const float* wo_raw = (const float*)d_in[3];
  const float* bo = (const float*)d_in[4];
  float* out = (float*)d_out;

  char* ws = (char*)d_ws;
  bf16* qw = (bf16*)(ws);                       // 16 MiB
  bf16* kw = (bf16*)(ws + 16777216);            // 16 MiB
  bf16* vw = (bf16*)(ws + 33554432);            // 16 MiB
  bf16* wqkvT = (bf16*)(ws + 50331648);         // 6 MiB (phase 1-2)
  float* cosT = (float*)(ws + 56623104);        // 256 KiB (phase 1-2)
  float* sinT = (float*)(ws + 56885248);        // 256 KiB (phase 1-2)
  bf16* ow = (bf16*)(ws + 50331648);            // 16 MiB (phase 3-4, overlays above)
  bf16* woT = (bf16*)(ws);                      // 2 MiB (phase 3.5-4, overlays qw)
  bf16* xb = (bf16*)d_out;                      // 16.8 MiB scratch in d_out (phase 1-2)

  static bool attr_set = false;
  if (!attr_set) {
    (void)hipFuncSetAttribute((const void*)qkv128_kernel,
                              hipFuncAttributeMaxDynamicSharedMemorySize, 163840);
    (void)hipFuncSetAttribute((const void*)outproj128_kernel,
                              hipFuncAttributeMaxDynamicSharedMemorySize, 163840);
    attr_set = true;
  }

  prep_kernel<<<11520, 256, 0, stream>>>(x_raw, xb, wqkv_raw, wqkvT, cosT, sinT);

  qkv128_kernel<<<dim3((BATCH * SEQ / 128) * (F3 / 256)), 512, 147456, stream>>>(
      xb, wqkvT, bqkv, qw, kw, vw, cosT, sinT);
  attn32_kernel<<<dim3(BATCH * NH * (SEQ / 256)), 512, 0, stream>>>(qw, kw, vw, ow);

  transpose_f32_bf16<<<dim3(EMB / 32, EMB / 32), 256, 0, stream>>>(wo_raw, woT, EMB, EMB);
  outproj128_kernel<<<dim3((BATCH * SEQ / 128) * (EMB / 256)), 512, 147456, stream>>>(
      ow, woT, bo, out);
}

// Round 15
// 249.477 us; speedup vs baseline: 1.0756x; 1.0185x over previous
//
#include <hip/hip_runtime.h>
#include <stdint.h>
#include <stddef.h>

typedef __bf16 bf16;
typedef __attribute__((ext_vector_type(8))) __bf16 bf16x8;
typedef __attribute__((ext_vector_type(4))) __bf16 bf16x4;
typedef __attribute__((ext_vector_type(4))) float f32x4;
typedef __attribute__((ext_vector_type(16))) float f32x16;
typedef __attribute__((ext_vector_type(4))) float float4v;
typedef __attribute__((ext_vector_type(4))) uint32_t u32x4;

#define BATCH 4
#define SEQ   2048
#define EMB   1024
#define NH    16
#define HD    64
#define F3    3072   // 3*EMB

#define MFMA16(a, b, c) __builtin_amdgcn_mfma_f32_16x16x32_bf16((a), (b), (c), 0, 0, 0)
#define MFMA32(a, b, c) __builtin_amdgcn_mfma_f32_32x32x16_bf16((a), (b), (c), 0, 0, 0)

// 2^x as a single v_exp_f32, emitted BY THE COMPILER (hazard nops included).
// R10: raw asm hides the TRANS wait-state hazard (wrong results); R9: libm
// exp2f is +30% VALU (OCML range handling). Builtin = correct middle path.
__device__ __forceinline__ float exp2_fast(float x) {
  return __builtin_amdgcn_exp2f(x);
}

// async global->LDS, 16B per lane. lds ptr must be wave-uniform; lane i lands at l + i*16B.
__device__ __forceinline__ void gload_lds16(const bf16* g, bf16* l) {
  __builtin_amdgcn_global_load_lds(
      (const __attribute__((address_space(1))) uint32_t*)g,
      (__attribute__((address_space(3))) uint32_t*)l, 16, 0, 0);
}

// ---------------------------------------------------------------------------
// 32x32 tile transpose+convert helper (shared by prep_kernel and the wo pass).
// ---------------------------------------------------------------------------
__device__ __forceinline__ void transpose_tile32(const float* __restrict__ in,
                                                 bf16* __restrict__ out,
                                                 int R, int C, int bx, int by) {
  __shared__ bf16 tile[32][33];
  const int tx = threadIdx.x & 31;
  const int ty = threadIdx.x >> 5;  // 0..7
  const int c0 = bx * 32, r0 = by * 32;
#pragma unroll
  for (int kk = 0; kk < 4; ++kk) {
    int r = ty + kk * 8;
    tile[r][tx] = (bf16)in[(size_t)(r0 + r) * C + c0 + tx];
  }
  __syncthreads();
#pragma unroll
  for (int kk = 0; kk < 4; ++kk) {
    int r = ty + kk * 8;
    out[(size_t)(c0 + r) * R + r0 + tx] = tile[tx][r];
  }
}

// ---------------------------------------------------------------------------
// Fused prep: region-dispatched by blockIdx.
//   [0, 8192)        : convert x f32 -> bf16 (2M float4 groups, exact fit)
//   [8192, 11264)    : transpose wqkv [1024][3072] f32 -> wqkvT [3072][1024] bf16
//   [11264, 11520)   : RoPE cos/sin table (2048 pos x 32 d1, f32)
// ---------------------------------------------------------------------------
__global__ __launch_bounds__(256) void prep_kernel(const float* __restrict__ x_raw,
                                                   bf16* __restrict__ xb,
                                                   const float* __restrict__ wqkv_raw,
                                                   bf16* __restrict__ wqkvT,
                                                   float* __restrict__ cosT,
                                                   float* __restrict__ sinT) {
  const int blk = blockIdx.x;
  if (blk < 8192) {
    int i = blk * 256 + threadIdx.x;   // 8192*256 == BATCH*SEQ*EMB/4 exactly
    float4v v = ((const float4v*)x_raw)[i];
    bf16x4 o;
#pragma unroll
    for (int k = 0; k < 4; ++k) o[k] = (bf16)v[k];
    ((bf16x4*)xb)[i] = o;
  } else if (blk < 11264) {
    int idx = blk - 8192;              // 3072 tiles: 96 col-tiles x 32 row-tiles
    transpose_tile32(wqkv_raw, wqkvT, EMB, F3, idx % 96, idx / 96);
  } else {
    int idx = (blk - 11264) * 256 + threadIdx.x;   // 65536
    int pos = idx >> 5, d1 = idx & 31;
    float inv = powf(10000.0f, -(float)(2 * d1) / 64.0f);
    float th = (float)pos * inv;
    cosT[idx] = cosf(th);
    sinT[idx] = sinf(th);
  }
}

// ---------------------------------------------------------------------------
// Standalone transpose (wo only; must run after attn frees the woT region).
// ---------------------------------------------------------------------------
__global__ __launch_bounds__(256) void transpose_f32_bf16(const float* __restrict__ in,
                                                          bf16* __restrict__ out,
                                                          int R, int C) {
  transpose_tile32(in, out, R, C, blockIdx.x, blockIdx.y);
}

// ---------------------------------------------------------------------------
// 64x256 / BK=64 double-buffered MFMA GEMM core, 2 blocks/CU.
//  - per-buffer 40 KB (A 64x64 = 8 KB + B 256x64 = 32 KB), dbuf = 80 KB LDS
//    => 2 co-resident blocks per CU: one block's MFMA fills the other's
//    vmcnt/barrier drains (m114 wave-level overlap; R6/R11 occupancy lesson).
//  - minimum 2-phase template (guide T3 recipe): STAGE(next) -> ds_read(cur)
//    -> lgkmcnt(0) -> setprio(1) 16xMFMA setprio(0) -> vmcnt(0) -> barrier.
//  - same 8x8 XOR staging involution as prior verified cores (granule ^= row&7
//    on pre-swizzled global source, linear LDS dest, swizzled ds_read).
//  - 8 waves = 2M x 4N; per-wave C = 32x64 -> acc[2][4] (32 VGPR acc; low
//    pressure aims for VGPR <= 128 naturally — NOT forced, per R7 lesson).
// ---------------------------------------------------------------------------
__device__ __forceinline__ void gemm64_core(bf16* lds,
                                            const bf16* __restrict__ Abase,
                                            const bf16* __restrict__ Bbase,
                                            f32x4 (&acc)[2][4]) {
  const int tid = threadIdx.x;
  const int w = tid >> 6, lane = tid & 63;
  const int lhi = lane >> 4, llo = lane & 15, l7 = llo & 7;
  const int wr = w >> 2, wc = w & 3;          // 2M x 4N wave grid
  const int srow = lane >> 3;                 // staging row within 8-row chunk
  const int sk16 = (lane & 7) ^ srow;         // pre-swizzled global 16B granule
  const size_t gA_lane = (size_t)(w * 8 + srow) * EMB + sk16 * 8;    // 64 rows
  const size_t gB_lane = (size_t)(w * 16 + srow) * EMB + sk16 * 8;   // 128 rows/call

  const int ka0 = (lhi * 8) ^ (l7 << 3);
  const int ka1 = (32 + lhi * 8) ^ (l7 << 3);
  const int arow = (wr * 32 + llo) * 64;      // A frag row base (elems)
  const int brow = (wc * 64 + llo) * 64;      // B frag row base (elems)

#pragma unroll
  for (int i = 0; i < 2; ++i)
#pragma unroll
    for (int j = 0; j < 4; ++j) acc[i][j] = (f32x4){0.f, 0.f, 0.f, 0.f};

  // buffer c occupies [c*20480, c*20480+20480): A at +0 (4096), B at +4096 (16384)
#define ASTAGE(baseptr, c) \
  gload_lds16((baseptr) + gA_lane, lds + (c) * 20480 + w * 512)
#define BSTAGE(baseptr, ldsoff)                               \
  do {                                                        \
    bf16* _l = lds + (ldsoff) + w * 1024;                     \
    gload_lds16((baseptr) + gB_lane, _l);                     \
    gload_lds16((baseptr) + gB_lane + 8 * EMB, _l + 512);     \
  } while (0)

  // prologue: tile 0 into buffer 0
  ASTAGE(Abase, 0);
  BSTAGE(Bbase, 4096);
  BSTAGE(Bbase + 128 * EMB, 4096 + 8192);
  asm volatile("s_waitcnt vmcnt(0)" ::: "memory");
  __builtin_amdgcn_s_barrier();

#pragma unroll 1
  for (int t = 0; t < 16; ++t) {
    const int cur = t & 1;
    const bf16* ldsA = lds + cur * 20480 + arow;
    const bf16* ldsB = lds + cur * 20480 + 4096 + brow;
    // stage next tile into the alternate buffer (issue BEFORE reads/MFMA)
    if (t < 15) {
      const int alt = cur ^ 1;
      const int k1 = (t + 1) * 64;
      ASTAGE(Abase + k1, alt);
      BSTAGE(Bbase + k1, alt * 20480 + 4096);
      BSTAGE(Bbase + k1 + 128 * EMB, alt * 20480 + 4096 + 8192);
    }
    bf16x8 a[2][2], b[4][2];
#pragma unroll
    for (int i = 0; i < 2; ++i) {
      a[i][0] = *(const bf16x8*)(ldsA + i * 1024 + ka0);
      a[i][1] = *(const bf16x8*)(ldsA + i * 1024 + ka1);
    }
#pragma unroll
    for (int j = 0; j < 4; ++j) {
      b[j][0] = *(const bf16x8*)(ldsB + j * 1024 + ka0);
      b[j][1] = *(const bf16x8*)(ldsB + j * 1024 + ka1);
    }
    asm volatile("s_waitcnt lgkmcnt(0)" ::: "memory");
    __builtin_amdgcn_sched_barrier(0);
    __builtin_amdgcn_s_setprio(1);
#pragma unroll
    for (int i = 0; i < 2; ++i)
#pragma unroll
      for (int j = 0; j < 4; ++j) {
        acc[i][j] = MFMA16(a[i][0], b[j][0], acc[i][j]);
        acc[i][j] = MFMA16(a[i][1], b[j][1], acc[i][j]);
      }
    __builtin_amdgcn_s_setprio(0);
    if (t < 15) {
      asm volatile("s_waitcnt vmcnt(0)" ::: "memory");
      __builtin_amdgcn_s_barrier();
    }
  }
#undef ASTAGE
#undef BSTAGE
}

// ---------------------------------------------------------------------------
// QKV GEMM (64x256 dbuf core) + bias + RoPE + scatter epilogue.
// Grid 1536 (128 Mtiles x 12 Ntiles), 2 blk/CU => 3 paired rounds; 1536%8==0.
// Q is prescaled by 0.125*log2(e) so attn can use v_exp_f32 (2^x) directly.
// ---------------------------------------------------------------------------
__global__ __launch_bounds__(512, 2) void qkv64_kernel(
    const bf16* __restrict__ x, const bf16* __restrict__ wT,
    const float* __restrict__ bias, bf16* __restrict__ qo, bf16* __restrict__ ko,
    bf16* __restrict__ vo, const float* __restrict__ cosT,
    const float* __restrict__ sinT) {
  extern __shared__ __align__(16) bf16 ldsb[];
  const int orig = blockIdx.x;
  const int wg = (orig & 7) * 192 + (orig >> 3);   // 192 contiguous wgs per XCD
  const int bx = wg % 12, by = wg / 12;
  const int row_a0 = by * 64, row_b0 = bx * 256;

  f32x4 acc[2][4];
  gemm64_core(ldsb, x + (size_t)row_a0 * EMB, wT + (size_t)row_b0 * EMB, acc);

  const int tid = threadIdx.x;
  const int w = tid >> 6, lane = tid & 63;
  const int lhi = lane >> 4, llo = lane & 15;
  const int wr = w >> 2, wc = w & 3;

  const int f0 = row_b0 + wc * 64;      // wave col base, 64-aligned
  const int part = f0 >> 10;            // 0=Q 1=K 2=V
  const int hh = (f0 & 1023) >> 6;      // head
  const int m_base = row_a0 + wr * 32;

  float bvals[4];
#pragma unroll
  for (int j = 0; j < 4; ++j) bvals[j] = bias[f0 + j * 16 + llo];

  if (part == 2) {
#pragma unroll
    for (int mi = 0; mi < 2; ++mi) {
      int m0 = m_base + mi * 16 + lhi * 4;
      int bb = m0 >> 11, pos0 = m0 & 2047;
#pragma unroll
      for (int j = 0; j < 4; ++j) {
        int dd = j * 16 + llo;
        bf16x4 pk;
#pragma unroll
        for (int r = 0; r < 4; ++r) pk[r] = (bf16)(acc[mi][j][r] + bvals[j]);
        *(bf16x4*)(vo + ((size_t)(bb * NH + hh) * HD + dd) * SEQ + pos0) = pk;
      }
    }
  } else {
    bf16* dst = (part == 0) ? qo : ko;
    // exp2 fold: Q carries 1/sqrt(64) * log2(e) so attn uses v_exp_f32 (2^x)
    // without the per-score multiply. K unscaled. (Numerics verified R9/R11.)
    const float qs = (part == 0) ? 0.18033688f : 1.0f;
#pragma unroll
    for (int mi = 0; mi < 2; ++mi) {
#pragma unroll
      for (int r = 0; r < 4; ++r) {
        int m = m_base + mi * 16 + lhi * 4 + r;
        int bb = m >> 11, pos = m & 2047;
        size_t base = ((size_t)(bb * NH + hh) * SEQ + pos) * HD;
#pragma unroll
        for (int j = 0; j < 2; ++j) {
          int d1 = j * 16 + llo;
          float x1 = acc[mi][j][r] + bvals[j];
          float x2 = acc[mi][j + 2][r] + bvals[j + 2];
          float cth = cosT[pos * 32 + d1];
          float sth = sinT[pos * 32 + d1];
          dst[base + d1] = (bf16)((x1 * cth - x2 * sth) * qs);
          dst[base + d1 + 32] = (bf16)((x2 * cth + x1 * sth) * qs);
        }
      }
    }
  }
}

// ---------------------------------------------------------------------------
// Output projection on the 64x256 dbuf core.
// Grid 512 (128 x 4) = exactly one full round at 2 blk/CU, zero tail.
// ---------------------------------------------------------------------------
__global__ __launch_bounds__(512, 2) void outproj64_kernel(
    const bf16* __restrict__ a_in, const bf16* __restrict__ wT,
    const float* __restrict__ bo, float* __restrict__ out) {
  extern __shared__ __align__(16) bf16 ldsb[];
  const int orig = blockIdx.x;
  const int wg = (orig & 7) * 64 + (orig >> 3);   // 512 % 8 == 0
  const int bx = wg % 4, by = wg / 4;
  const int row_a0 = by * 64, row_b0 = bx * 256;

  f32x4 acc[2][4];
  gemm64_core(ldsb, a_in + (size_t)row_a0 * EMB, wT + (size_t)row_b0 * EMB, acc);

  const int tid = threadIdx.x;
  const int w = tid >> 6, lane = tid & 63;
  const int lhi = lane >> 4, llo = lane & 15;
  const int wr = w >> 2, wc = w & 3;

  const int col0 = row_b0 + wc * 64;
  const int m_base = row_a0 + wr * 32;
  float bvals[4];
#pragma unroll
  for (int j = 0; j < 4; ++j) bvals[j] = bo[col0 + j * 16 + llo];
#pragma unroll
  for (int mi = 0; mi < 2; ++mi) {
#pragma unroll
    for (int r = 0; r < 4; ++r) {
      int m = m_base + mi * 16 + lhi * 4 + r;
#pragma unroll
      for (int j = 0; j < 4; ++j)
        out[(size_t)m * EMB + col0 + j * 16 + llo] = acc[mi][j][r] + bvals[j];
    }
  }
}

// ---------------------------------------------------------------------------
// Flash attention v5g (R11/R14-verified best: ~81 us, 853 TF): 8 waves x 32
// q-rows, QBLK=256, 32x32x16 MFMA, swapped QK^T, in-register softmax (T12
// cvt_pk+permlane), exp2 fold via compiler builtin. VGPR 60 / occ ~34.5%.
// Attention is CLOSED here (R6/R7/R9/R10/R13 rejections documented).
// ---------------------------------------------------------------------------
__global__ __launch_bounds__(512, 2) void attn32_kernel(const bf16* __restrict__ q,
                                                        const bf16* __restrict__ k,
                                                        const bf16* __restrict__ vT,
                                                        bf16* __restrict__ o) {
  __shared__ __align__(16) bf16 smem[16384];  // K dbuf 2x4096, V dbuf 2x4096 elems

  const int tid = threadIdx.x, w = tid >> 6, lane = tid & 63;
  const int l31 = lane & 31, hi = lane >> 5;
  const int bidx = blockIdx.x;
  const int vblk = (bidx & 7) * 64 + (bidx >> 3);  // XCD-contiguous remap (512 blocks)
  const int qt = vblk & 7, bh = vblk >> 3;         // 8 q-tiles of 256, bh in [0,64)
  const bf16* qbase = q + (size_t)bh * SEQ * HD + qt * 256 * HD;
  const bf16* kbase = k + (size_t)bh * SEQ * HD;
  const bf16* vbase = vT + (size_t)bh * HD * SEQ;

  const int rowc = lane >> 3;                     // row within 8-row chunk
  const int sw8 = (lane & 7) ^ rowc;              // staging XOR swizzle (16B granules)

  // Q -> registers: B-frag qf[c] = Q[q=l31][c*16 + hi*8 + j], rows w*32+l31
  bf16x8 qf[4];
  {
    const bf16* qrow = qbase + (size_t)(w * 32 + l31) * HD;
#pragma unroll
    for (int c = 0; c < 4; ++c) qf[c] = *(const bf16x8*)(qrow + c * 16 + hi * 8);
  }

  // stage tile 0: waves 0-3 K (64tok x 64d), waves 4-7 V^T (64d x 64tok)
  if (w < 4) {
#pragma unroll
    for (int c = 0; c < 2; ++c) {
      int ch = w * 2 + c, row = ch * 8 + rowc;
      gload_lds16(kbase + (size_t)row * HD + sw8 * 8, &smem[ch * 512]);
    }
  } else {
#pragma unroll
    for (int c = 0; c < 2; ++c) {
      int ch = (w - 4) * 2 + c, row = ch * 8 + rowc;
      gload_lds16(vbase + (size_t)row * SEQ + sw8 * 8, &smem[8192 + ch * 512]);
    }
  }
  __syncthreads();

  float rsum = 0.f;
  f32x16 oacc[2];
#pragma unroll
  for (int r = 0; r < 16; ++r) { oacc[0][r] = 0.f; oacc[1][r] = 0.f; }

  const int swz = (l31 & 7);  // row&7 for frag reads (rows = tile_base + l31)

  for (int kb = 0; kb < 32; ++kb) {
    bf16* Kc = smem + (kb & 1) * 4096;
    bf16* Vc = smem + 8192 + (kb & 1) * 4096;
    // prefetch next tile into alt buffers
    if (kb < 31) {
      int kpos = (kb + 1) * 64;
      if (w < 4) {
        bf16* Kn = smem + ((kb + 1) & 1) * 4096;
#pragma unroll
        for (int c = 0; c < 2; ++c) {
          int ch = w * 2 + c, row = ch * 8 + rowc;
          gload_lds16(kbase + (size_t)(kpos + row) * HD + sw8 * 8, &Kn[ch * 512]);
        }
      } else {
        bf16* Vn = smem + 8192 + ((kb + 1) & 1) * 4096;
#pragma unroll
        for (int c = 0; c < 2; ++c) {
          int ch = (w - 4) * 2 + c, row = ch * 8 + rowc;
          gload_lds16(vbase + (size_t)row * SEQ + kpos + sw8 * 8, &Vn[ch * 512]);
        }
      }
    }

    // ---- QK^T: S^T[tok][q], token tiles tt=0,1; k-chunks c of 16 dims
    f32x16 st0, st1;
#pragma unroll
    for (int r = 0; r < 16; ++r) { st0[r] = 0.f; st1[r] = 0.f; }
    __builtin_amdgcn_s_setprio(1);
#pragma unroll
    for (int c = 0; c < 4; ++c) {
      bf16x8 kf0 = *(const bf16x8*)&Kc[l31 * 64 + (((c * 2 + hi) ^ swz) * 8)];
      bf16x8 kf1 = *(const bf16x8*)&Kc[(32 + l31) * 64 + (((c * 2 + hi) ^ swz) * 8)];
      st0 = MFMA32(kf0, qf[c], st0);
      st1 = MFMA32(kf1, qf[c], st1);
    }
    __builtin_amdgcn_s_setprio(0);

    // ---- softmax: p = 2^s via builtin exp2 (Q prescaled by log2e/8)
#pragma unroll
    for (int r = 0; r < 16; ++r) {
      st0[r] = exp2_fast(st0[r]);
      st1[r] = exp2_fast(st1[r]);
    }
    {
      float a0 = 0.f, a1 = 0.f, a2 = 0.f, a3 = 0.f;
#pragma unroll
      for (int r = 0; r < 16; r += 4) {
        a0 += st0[r];     a1 += st0[r + 1];
        a2 += st0[r + 2]; a3 += st0[r + 3];
      }
#pragma unroll
      for (int r = 0; r < 16; r += 4) {
        a0 += st1[r];     a1 += st1[r + 1];
        a2 += st1[r + 2]; a3 += st1[r + 3];
      }
      rsum += (a0 + a1) + (a2 + a3);
    }

    // ---- P -> PV A-frags (T12): per (tt,c1): 4 cvt_pk + 2 permlane32_swap.
    bf16x8 pa[4];
#pragma unroll
    for (int tt = 0; tt < 2; ++tt) {
#pragma unroll
      for (int c1 = 0; c1 < 2; ++c1) {
        float s0 = tt ? st1[c1 * 8 + 0] : st0[c1 * 8 + 0];
        float s1 = tt ? st1[c1 * 8 + 1] : st0[c1 * 8 + 1];
        float s2 = tt ? st1[c1 * 8 + 2] : st0[c1 * 8 + 2];
        float s3 = tt ? st1[c1 * 8 + 3] : st0[c1 * 8 + 3];
        float s4 = tt ? st1[c1 * 8 + 4] : st0[c1 * 8 + 4];
        float s5 = tt ? st1[c1 * 8 + 5] : st0[c1 * 8 + 5];
        float s6 = tt ? st1[c1 * 8 + 6] : st0[c1 * 8 + 6];
        float s7 = tt ? st1[c1 * 8 + 7] : st0[c1 * 8 + 7];
        uint32_t a0, a1, b0, b1;
        asm("v_cvt_pk_bf16_f32 %0, %1, %2" : "=v"(a0) : "v"(s0), "v"(s1));
        asm("v_cvt_pk_bf16_f32 %0, %1, %2" : "=v"(a1) : "v"(s2), "v"(s3));
        asm("v_cvt_pk_bf16_f32 %0, %1, %2" : "=v"(b0) : "v"(s4), "v"(s5));
        asm("v_cvt_pk_bf16_f32 %0, %1, %2" : "=v"(b1) : "v"(s6), "v"(s7));
        asm("v_permlane32_swap_b32 %0, %1" : "+v"(a0), "+v"(b0));
        asm("v_permlane32_swap_b32 %0, %1" : "+v"(a1), "+v"(b1));
        u32x4 uv = {a0, a1, b0, b1};
        pa[tt * 2 + c1] = __builtin_bit_cast(bf16x8, uv);
      }
    }

    // ---- O += P V : A=pa[c] (tokens c*16..+15), B=V^T rows d=jt*32+l31
    __builtin_amdgcn_s_setprio(1);
#pragma unroll
    for (int c = 0; c < 4; ++c) {
      bf16x8 v0 = *(const bf16x8*)&Vc[l31 * 64 + (((c * 2 + hi) ^ swz) * 8)];
      bf16x8 v1 = *(const bf16x8*)&Vc[(32 + l31) * 64 + (((c * 2 + hi) ^ swz) * 8)];
      oacc[0] = MFMA32(pa[c], v0, oacc[0]);
      oacc[1] = MFMA32(pa[c], v1, oacc[1]);
    }
    __builtin_amdgcn_s_setprio(0);

    __syncthreads();  // prefetch landed + guards buffer reuse
  }

  // epilogue: rsum(q=l31) split across lane halves -> combine; redistribute
  // to C-layout row owners via shfl; normalize and write.
  rsum += __shfl_xor(rsum, 32);
  const int bb = bh >> 4, hh = bh & 15;
#pragma unroll
  for (int r = 0; r < 16; ++r) {
    int qrow = (r & 3) + 8 * (r >> 2) + 4 * hi;
    float inv = 1.0f / __shfl(rsum, qrow);
    int pos = qt * 256 + w * 32 + qrow;
    size_t base = ((size_t)bb * SEQ + pos) * EMB + hh * HD;
    o[base + l31] = (bf16)(oacc[0][r] * inv);
    o[base + 32 + l31] = (bf16)(oacc[1][r] * inv);
  }
}

// ---------------------------------------------------------------------------
// Workspace layout (<= 64 MiB used):
//   [0, 16M)   qw [b,h,s,d] bf16   (later woT @0..2M after attn)
//   [16M,32M)  kw;  [32M,48M) vw [b,h,d,s]
//   [48M,64M)  phase1-2: wqkvT (6M) + cosT/sinT; phase3-4: ow bf16 (16M)
// d_out (33.5 MB f32) doubles as xb scratch (16.8 MB bf16) in phases 1-2.
// ---------------------------------------------------------------------------
extern "C" void kernel_launch(void* const* d_in, const int* in_sizes, int n_in,
                              void* d_out, int out_size, void* d_ws, size_t ws_size,
                              hipStream_t stream) {
  const float* x_raw = (const float*)d_in[0];
  const float* wqkv_raw = (const float*)d_in[1];
  const float* bqkv = (const float*)d_in[2];
  const float* wo_raw = (const float*)d_in[3];
  const float* bo = (const float*)d_in[4];
  float* out = (float*)d_out;

  char* ws = (char*)d_ws;
  bf16* qw = (bf16*)(ws);                       // 16 MiB
  bf16* kw = (bf16*)(ws + 16777216);            // 16 MiB
  bf16* vw = (bf16*)(ws + 33554432);            // 16 MiB
  bf16* wqkvT = (bf16*)(ws + 50331648);         // 6 MiB (phase 1-2)
  float* cosT = (float*)(ws + 56623104);        // 256 KiB (phase 1-2)
  float* sinT = (float*)(ws + 56885248);        // 256 KiB (phase 1-2)
  bf16* ow = (bf16*)(ws + 50331648);            // 16 MiB (phase 3-4, overlays above)
  bf16* woT = (bf16*)(ws);                      // 2 MiB (phase 3.5-4, overlays qw)
  bf16* xb = (bf16*)d_out;                      // 16.8 MiB scratch in d_out (phase 1-2)

  static bool attr_set = false;
  if (!attr_set) {
    (void)hipFuncSetAttribute((const void*)qkv64_kernel,
                              hipFuncAttributeMaxDynamicSharedMemorySize, 163840);
    (void)hipFuncSetAttribute((const void*)outproj64_kernel,
                              hipFuncAttributeMaxDynamicSharedMemorySize, 163840);
    attr_set = true;
  }

  prep_kernel<<<11520, 256, 0, stream>>>(x_raw, xb, wqkv_raw, wqkvT, cosT, sinT);

  qkv64_kernel<<<dim3((BATCH * SEQ / 64) * (F3 / 256)), 512, 81920, stream>>>(
      xb, wqkvT, bqkv, qw, kw, vw, cosT, sinT);
  attn32_kernel<<<dim3(BATCH * NH * (SEQ / 256)), 512, 0, stream>>>(qw, kw, vw, ow);

  transpose_f32_bf16<<<dim3(EMB / 32, EMB / 32), 256, 0, stream>>>(wo_raw, woT, EMB, EMB);
  outproj64_kernel<<<dim3((BATCH * SEQ / 64) * (EMB / 256)), 512, 81920, stream>>>(
      ow, woT, bo, out);
}